// Round 8
// baseline (78.075 us; speedup 1.0000x reference)
//
#include <hip/hip_runtime.h>
#include <hip/hip_bf16.h>

// Problem constants (N,C,H,W) = (32,256,56,56), GROUPS=8
#define NN 32
#define CC 256
#define HW 3136            // H*W
#define HW4 784            // float4 per (n,c) plane
#define CHW 802816
#define CHW4 200704        // float4 per sample
#define NCHW 25690112
#define GROUPS 8
#define CPG 32             // C/GROUPS
#define NHW 100352         // N*H*W (per-channel count)
#define GHW 100352         // CPG*HW (per-group count)
#define EPSF 1e-5f

#define NPOS4 25088        // total float4 positions = NN*HW4 (= 98*256 exactly)
#define POSBLK 98          // position blocks (256 f4-positions each)
#define CGS 16             // channel groups for chansum (16 ch each)
#define CPB 16             // channels per chansum block (CC/CGS)
#define NPT2 POSBLK        // 98 T^2 partials

// ---- kernel 1: per-(n,c) plane sums; one wave = one full plane -----------
// grid = 2048 blocks (4 waves = 4 planes per block). HBM-bound pass.
__global__ __launch_bounds__(256) void plane_stats_kernel(
    const float4* __restrict__ x4, float* __restrict__ S1, float* __restrict__ S2)
{
    const int wave = threadIdx.x >> 6, lane = threadIdx.x & 63;
    const int nc = blockIdx.x * 4 + wave;
    const float4* p = x4 + (size_t)nc * HW4;
    float s1 = 0.f, s2 = 0.f;
    #pragma unroll
    for (int j = 0; j < 12; ++j) {             // 12*64 = 768 always valid
        float4 v = p[lane + j * 64];
        s1 += v.x + v.y + v.z + v.w;
        s2 += v.x*v.x + v.y*v.y + v.z*v.z + v.w*v.w;
    }
    if (lane < 16) {                           // tail 768..783
        float4 v = p[768 + lane];
        s1 += v.x + v.y + v.z + v.w;
        s2 += v.x*v.x + v.y*v.y + v.z*v.z + v.w*v.w;
    }
    #pragma unroll
    for (int off = 32; off; off >>= 1) {
        s1 += __shfl_down(s1, off, 64);
        s2 += __shfl_down(s2, off, 64);
    }
    if (lane == 0) { S1[nc] = s1; S2[nc] = s2; }
}

// ---- kernel 2: position-parallel partial channel sums --------------------
// grid = CGS*POSBLK = 1568 blocks (6.1 waves/SIMD); thread = one f4 position,
// 16 fully-unrolled independent float4 loads; no reductions, no LDS.
__global__ __launch_bounds__(256) void chansum_kernel(
    const float4* __restrict__ x4, float4* __restrict__ pT4)
{
    const int cg = blockIdx.x / POSBLK;
    const int pb = blockIdx.x % POSBLK;
    const int pos = pb * 256 + threadIdx.x;    // 0..25087, exact fit
    const int n = pos / HW4;
    const int p4 = pos - n * HW4;
    const float4* q = x4 + (size_t)n * CHW4 + (size_t)(cg * CPB) * HW4 + p4;
    float4 T = make_float4(0.f, 0.f, 0.f, 0.f);
    #pragma unroll
    for (int c = 0; c < CPB; ++c) {
        float4 v = q[(size_t)c * HW4];
        T.x += v.x; T.y += v.y; T.z += v.z; T.w += v.w;
    }
    pT4[(size_t)cg * NPOS4 + pos] = T;
}

// ---- kernel 3: fold 16 channel groups, square, block-reduce -> pT2[98] ---
__global__ __launch_bounds__(256) void combine_kernel(
    const float4* __restrict__ pT4, float* __restrict__ pT2)
{
    const int tid = threadIdx.x;
    const int pos = blockIdx.x * 256 + tid;
    float4 T = make_float4(0.f, 0.f, 0.f, 0.f);
    #pragma unroll
    for (int cg = 0; cg < CGS; ++cg) {
        float4 v = pT4[(size_t)cg * NPOS4 + pos];
        T.x += v.x; T.y += v.y; T.z += v.z; T.w += v.w;
    }
    float t2 = T.x*T.x + T.y*T.y + T.z*T.z + T.w*T.w;
    #pragma unroll
    for (int off = 32; off; off >>= 1) t2 += __shfl_down(t2, off, 64);
    __shared__ float sh[4];
    const int wave = tid >> 6, lane = tid & 63;
    if (lane == 0) sh[wave] = t2;
    __syncthreads();
    if (tid == 0) pT2[blockIdx.x] = sh[0] + sh[1] + sh[2] + sh[3];
}

// ---- kernel 4: all stats -> gates -> per-(n,c) affine coeffs A,B ---------
__global__ __launch_bounds__(256) void finalize_kernel(
    const float* __restrict__ S1, const float* __restrict__ S2,
    const float* __restrict__ partialT2,
    const float* __restrict__ weight, const float* __restrict__ bias,
    const float* __restrict__ gate_logits, const float* __restrict__ diag_proj,
    float* __restrict__ A, float* __restrict__ B)
{
    const int tid = threadIdx.x;
    __shared__ float sh_mu_b[CC], sh_rs_b[CC];
    __shared__ float sh_mu_g[NN * GROUPS], sh_rs_g[NN * GROUPS];
    __shared__ float sh_mu_l[NN], sh_rs_l[NN];
    __shared__ float sh_red1[4], sh_red2[4], sh_red3[4], sh_red4[4];
    __shared__ float sh_gate[3];

    const float inv_NHW  = 1.f / (float)NHW;
    const float inv_CHW  = 1.f / (float)CHW;
    const float inv_GHW  = 1.f / (float)GHW;
    const float inv_NCHW = 1.f / (float)NCHW;

    // BN: thread = channel
    const int c = tid;
    float s1 = 0.f, s2 = 0.f;
    for (int n = 0; n < NN; ++n) { s1 += S1[n * CC + c]; s2 += S2[n * CC + c]; }
    const float mu_b  = s1 * inv_NHW;
    const float var_b = s2 * inv_NHW - mu_b * mu_b;
    sh_mu_b[c] = mu_b;
    sh_rs_b[c] = rsqrtf(var_b + EPSF);

    // GN: thread = n*8+g
    const int ng_n = tid >> 3, ng_g = tid & 7;
    float s1g = 0.f, s2g = 0.f;
    for (int cc2 = 0; cc2 < CPG; ++cc2) {
        const int idx = ng_n * CC + ng_g * CPG + cc2;
        s1g += S1[idx]; s2g += S2[idx];
    }
    const float mu_g  = s1g * inv_GHW;
    const float var_g = s2g * inv_GHW - mu_g * mu_g;
    sh_mu_g[tid] = mu_g;
    sh_rs_g[tid] = rsqrtf(var_g + EPSF);

    // LN: reduce GN sums over the 8 groups of each sample
    float s1l = s1g, s2l = s2g;
    #pragma unroll
    for (int off = 1; off < 8; off <<= 1) {
        s1l += __shfl_xor(s1l, off, 64);
        s2l += __shfl_xor(s2l, off, 64);
    }
    float var_l_contrib = 0.f;
    if (ng_g == 0) {
        const float mu_l  = s1l * inv_CHW;
        const float var_l = s2l * inv_CHW - mu_l * mu_l;
        sh_mu_l[ng_n] = mu_l;
        sh_rs_l[ng_n] = rsqrtf(var_l + EPSF);
        var_l_contrib = var_l;
    }

    // T^2 partials
    float t2p = 0.f;
    for (int i = tid; i < NPT2; i += 256) t2p += partialT2[i];

    float r1 = var_b, r2 = s2, r3 = var_l_contrib, r4 = t2p;
    #pragma unroll
    for (int off = 32; off; off >>= 1) {
        r1 += __shfl_down(r1, off, 64);
        r2 += __shfl_down(r2, off, 64);
        r3 += __shfl_down(r3, off, 64);
        r4 += __shfl_down(r4, off, 64);
    }
    const int wave = tid >> 6, lane = tid & 63;
    if (lane == 0) { sh_red1[wave] = r1; sh_red2[wave] = r2; sh_red3[wave] = r3; sh_red4[wave] = r4; }
    __syncthreads();
    if (tid == 0) {
        const float sum_var_b = sh_red1[0] + sh_red1[1] + sh_red1[2] + sh_red1[3];
        const float total_x2  = sh_red2[0] + sh_red2[1] + sh_red2[2] + sh_red2[3];
        const float sum_var_l = sh_red3[0] + sh_red3[1] + sh_red3[2] + sh_red3[3];
        const float sum_T2    = sh_red4[0] + sh_red4[1] + sh_red4[2] + sh_red4[3];

        const float batch_var   = sum_var_b * (1.f / (float)CC);
        const float sample_var  = sum_var_l * (1.f / (float)NN);
        const float channel_var = total_x2 * inv_NCHW
                                - sum_T2 * inv_NHW * (1.f / ((float)CC * (float)CC));

        float desc[3];
        desc[0] = tanhf(logf(fmaxf(batch_var,   EPSF)));
        desc[1] = tanhf(logf(fmaxf(sample_var,  EPSF)));
        desc[2] = tanhf(logf(fmaxf(channel_var, EPSF)));

        float lg[3];
        #pragma unroll
        for (int i = 0; i < 3; ++i) {
            lg[i] = gate_logits[i] + diag_proj[i*3+0]*desc[0]
                                   + diag_proj[i*3+1]*desc[1]
                                   + diag_proj[i*3+2]*desc[2];
        }
        const float m = fmaxf(lg[0], fmaxf(lg[1], lg[2]));
        const float e0 = expf(lg[0]-m), e1 = expf(lg[1]-m), e2 = expf(lg[2]-m);
        const float inv = 1.f / (e0 + e1 + e2);
        sh_gate[0] = e0 * inv; sh_gate[1] = e1 * inv; sh_gate[2] = e2 * inv;
    }
    __syncthreads();

    const float g0 = sh_gate[0], g1 = sh_gate[1], g2 = sh_gate[2];
    for (int i = tid; i < NN * CC; i += 256) {
        const int n = i >> 8, ch = i & 255, g = ch >> 5;
        const float w = weight[ch], bi = bias[ch];
        const float rb = sh_rs_b[ch], rl = sh_rs_l[n], rg = sh_rs_g[n*8+g];
        const float mb = sh_mu_b[ch], ml = sh_mu_l[n], mg = sh_mu_g[n*8+g];
        const float scale = g0*rb + g1*rl + g2*rg;
        const float offs  = g0*mb*rb + g1*ml*rl + g2*mg*rg;
        A[i] = w * scale;
        B[i] = bi - w * offs;
    }
}

// ---- kernel 5: y = x*A[nc] + B[nc], one block per (n,c) plane ------------
__global__ __launch_bounds__(256) void apply_kernel(
    const float4* __restrict__ x4, const float* __restrict__ A,
    const float* __restrict__ B, float4* __restrict__ y4)
{
    const int nc = blockIdx.x;
    const float a = A[nc], b = B[nc];
    const float4* xp = x4 + (size_t)nc * HW4;
    float4* yp = y4 + (size_t)nc * HW4;
    for (int i = threadIdx.x; i < HW4; i += 256) {
        float4 v = xp[i];
        v.x = fmaf(v.x, a, b);
        v.y = fmaf(v.y, a, b);
        v.z = fmaf(v.z, a, b);
        v.w = fmaf(v.w, a, b);
        yp[i] = v;
    }
}

extern "C" void kernel_launch(void* const* d_in, const int* in_sizes, int n_in,
                              void* d_out, int out_size, void* d_ws, size_t ws_size,
                              hipStream_t stream) {
    const float* x           = (const float*)d_in[0];
    const float* weight      = (const float*)d_in[1];
    const float* bias        = (const float*)d_in[2];
    const float* gate_logits = (const float*)d_in[3];
    const float* diag_proj   = (const float*)d_in[4];
    float* out = (float*)d_out;

    float* ws   = (float*)d_ws;
    float* S1   = ws;                 // 8192
    float* S2   = ws + 8192;          // 8192
    float* A    = ws + 16384;         // 8192
    float* B    = ws + 24576;         // 8192
    float* pT2  = ws + 32768;         // 98 (pad to 128)
    float* pT4f = ws + 32896;         // CGS*NPOS4*4 = 1605632 floats (6.4 MB);
                                      // 32896*4 % 16 == 0 -> float4-aligned

    plane_stats_kernel<<<2048, 256, 0, stream>>>((const float4*)x, S1, S2);
    chansum_kernel<<<CGS * POSBLK, 256, 0, stream>>>((const float4*)x, (float4*)pT4f);
    combine_kernel<<<POSBLK, 256, 0, stream>>>((const float4*)pT4f, pT2);
    finalize_kernel<<<1, 256, 0, stream>>>(S1, S2, pT2, weight, bias,
                                           gate_logits, diag_proj, A, B);
    apply_kernel<<<NN * CC, 256, 0, stream>>>((const float4*)x, A, B, (float4*)out);
}

// Round 9
// 69.460 us; speedup vs baseline: 1.1240x; 1.1240x over previous
//
#include <hip/hip_runtime.h>
#include <hip/hip_bf16.h>

// Problem constants (N,C,H,W) = (32,256,56,56), GROUPS=8
#define NN 32
#define CC 256
#define HW 3136            // H*W
#define HW4 784            // float4 per (n,c) plane
#define CHW 802816
#define CHW4 200704        // float4 per sample
#define NCHW 25690112
#define GROUPS 8
#define CPG 32             // C/GROUPS
#define NHW 100352         // N*H*W (per-channel count)
#define GHW 100352         // CPG*HW (per-group count)
#define EPSF 1e-5f

#define PB8 98             // 8-f4 position blocks per sample (98*8 = 784)
#define NSTAT (NN*PB8)     // 3136 stats blocks
#define NPT2 NSTAT         // 3136 T^2 partials

// ---- kernel 1: ONE read of x -> per-(n,c,pb) channel partials + T^2 ------
// block = (n, pb of 8 f4-positions); lane = (c_local 0..7, p 0..7);
// iter k: wave covers channels (k*4+w)*8 + c_local at the block's 8 positions.
__global__ __launch_bounds__(256) void stats_kernel(
    const float4* __restrict__ x4,
    float* __restrict__ S1p, float* __restrict__ S2p,   // [NSTAT][256]
    float* __restrict__ pT2)                            // [NSTAT]
{
    const int bx = blockIdx.x;
    const int n = bx / PB8, pb = bx - n * PB8;
    const int tid = threadIdx.x;
    const int w = tid >> 6, lane = tid & 63;
    const int cl = lane >> 3;          // channel-local 0..7
    const int pl = lane & 7;           // position-local 0..7
    const int P0 = pb * 8;

    const float4* base = x4 + (size_t)n * CHW4 + P0 + pl;

    float s1a[8], s2a[8];
    float4 T = make_float4(0.f, 0.f, 0.f, 0.f);
    #pragma unroll
    for (int k = 0; k < 8; ++k) {
        const int c = (k * 4 + w) * 8 + cl;
        float4 v = base[(size_t)c * HW4];
        T.x += v.x; T.y += v.y; T.z += v.z; T.w += v.w;
        s1a[k] = v.x + v.y + v.z + v.w;
        s2a[k] = v.x*v.x + v.y*v.y + v.z*v.z + v.w*v.w;
    }

    // per-channel partials: reduce over the 8 p-lanes (consecutive lanes)
    #pragma unroll
    for (int k = 0; k < 8; ++k) {
        #pragma unroll
        for (int off = 1; off < 8; off <<= 1) {
            s1a[k] += __shfl_down(s1a[k], off, 64);
            s2a[k] += __shfl_down(s2a[k], off, 64);
        }
    }
    if (pl == 0) {
        #pragma unroll
        for (int k = 0; k < 8; ++k) {
            const int c = (k * 4 + w) * 8 + cl;
            S1p[(size_t)bx * 256 + c] = s1a[k];
            S2p[(size_t)bx * 256 + c] = s2a[k];
        }
    }

    // cross-channel T: reduce over the 8 c_local lanes (stride 8)
    #pragma unroll
    for (int off = 8; off < 64; off <<= 1) {
        T.x += __shfl_xor(T.x, off, 64);
        T.y += __shfl_xor(T.y, off, 64);
        T.z += __shfl_xor(T.z, off, 64);
        T.w += __shfl_xor(T.w, off, 64);
    }
    __shared__ float4 shT[4][8];
    if (lane < 8) shT[w][pl] = T;      // lane<8 => cl==0
    __syncthreads();
    if (tid < 8) {
        float4 a = shT[0][tid], b = shT[1][tid], c4 = shT[2][tid], d = shT[3][tid];
        const float tx = a.x + b.x + c4.x + d.x;
        const float ty = a.y + b.y + c4.y + d.y;
        const float tz = a.z + b.z + c4.z + d.z;
        const float tw = a.w + b.w + c4.w + d.w;
        float t2 = tx*tx + ty*ty + tz*tz + tw*tw;
        #pragma unroll
        for (int off = 1; off < 8; off <<= 1) t2 += __shfl_down(t2, off, 64);
        if (tid == 0) pT2[bx] = t2;
    }
}

// ---- kernel 2: fold 98 position-partials -> S1/S2[n*256+c] ---------------
__global__ __launch_bounds__(256) void fold_kernel(
    const float* __restrict__ S1p, const float* __restrict__ S2p,
    float* __restrict__ S1, float* __restrict__ S2)
{
    const int n = blockIdx.x, c = threadIdx.x;
    const float* p1 = S1p + (size_t)n * PB8 * 256 + c;
    const float* p2 = S2p + (size_t)n * PB8 * 256 + c;
    float a = 0.f, b = 0.f;
    #pragma unroll 14
    for (int pb = 0; pb < PB8; ++pb) {
        a += p1[(size_t)pb * 256];
        b += p2[(size_t)pb * 256];
    }
    S1[n * 256 + c] = a;
    S2[n * 256 + c] = b;
}

// ---- kernel 3: all stats -> gates -> per-(n,c) affine coeffs A,B ---------
__global__ __launch_bounds__(256) void finalize_kernel(
    const float* __restrict__ S1, const float* __restrict__ S2,
    const float* __restrict__ partialT2,
    const float* __restrict__ weight, const float* __restrict__ bias,
    const float* __restrict__ gate_logits, const float* __restrict__ diag_proj,
    float* __restrict__ A, float* __restrict__ B)
{
    const int tid = threadIdx.x;
    __shared__ float sh_mu_b[CC], sh_rs_b[CC];
    __shared__ float sh_mu_g[NN * GROUPS], sh_rs_g[NN * GROUPS];
    __shared__ float sh_mu_l[NN], sh_rs_l[NN];
    __shared__ float sh_red1[4], sh_red2[4], sh_red3[4], sh_red4[4];
    __shared__ float sh_gate[3];

    const float inv_NHW  = 1.f / (float)NHW;
    const float inv_CHW  = 1.f / (float)CHW;
    const float inv_GHW  = 1.f / (float)GHW;
    const float inv_NCHW = 1.f / (float)NCHW;

    // BN: thread = channel
    const int c = tid;
    float s1 = 0.f, s2 = 0.f;
    for (int n = 0; n < NN; ++n) { s1 += S1[n * CC + c]; s2 += S2[n * CC + c]; }
    const float mu_b  = s1 * inv_NHW;
    const float var_b = s2 * inv_NHW - mu_b * mu_b;
    sh_mu_b[c] = mu_b;
    sh_rs_b[c] = rsqrtf(var_b + EPSF);

    // GN: thread = n*8+g
    const int ng_n = tid >> 3, ng_g = tid & 7;
    float s1g = 0.f, s2g = 0.f;
    for (int cc2 = 0; cc2 < CPG; ++cc2) {
        const int idx = ng_n * CC + ng_g * CPG + cc2;
        s1g += S1[idx]; s2g += S2[idx];
    }
    const float mu_g  = s1g * inv_GHW;
    const float var_g = s2g * inv_GHW - mu_g * mu_g;
    sh_mu_g[tid] = mu_g;
    sh_rs_g[tid] = rsqrtf(var_g + EPSF);

    // LN: reduce GN sums over the 8 groups of each sample
    float s1l = s1g, s2l = s2g;
    #pragma unroll
    for (int off = 1; off < 8; off <<= 1) {
        s1l += __shfl_xor(s1l, off, 64);
        s2l += __shfl_xor(s2l, off, 64);
    }
    float var_l_contrib = 0.f;
    if (ng_g == 0) {
        const float mu_l  = s1l * inv_CHW;
        const float var_l = s2l * inv_CHW - mu_l * mu_l;
        sh_mu_l[ng_n] = mu_l;
        sh_rs_l[ng_n] = rsqrtf(var_l + EPSF);
        var_l_contrib = var_l;
    }

    // T^2 partials
    float t2p = 0.f;
    for (int i = tid; i < NPT2; i += 256) t2p += partialT2[i];

    float r1 = var_b, r2 = s2, r3 = var_l_contrib, r4 = t2p;
    #pragma unroll
    for (int off = 32; off; off >>= 1) {
        r1 += __shfl_down(r1, off, 64);
        r2 += __shfl_down(r2, off, 64);
        r3 += __shfl_down(r3, off, 64);
        r4 += __shfl_down(r4, off, 64);
    }
    const int wave = tid >> 6, lane = tid & 63;
    if (lane == 0) { sh_red1[wave] = r1; sh_red2[wave] = r2; sh_red3[wave] = r3; sh_red4[wave] = r4; }
    __syncthreads();
    if (tid == 0) {
        const float sum_var_b = sh_red1[0] + sh_red1[1] + sh_red1[2] + sh_red1[3];
        const float total_x2  = sh_red2[0] + sh_red2[1] + sh_red2[2] + sh_red2[3];
        const float sum_var_l = sh_red3[0] + sh_red3[1] + sh_red3[2] + sh_red3[3];
        const float sum_T2    = sh_red4[0] + sh_red4[1] + sh_red4[2] + sh_red4[3];

        const float batch_var   = sum_var_b * (1.f / (float)CC);
        const float sample_var  = sum_var_l * (1.f / (float)NN);
        const float channel_var = total_x2 * inv_NCHW
                                - sum_T2 * inv_NHW * (1.f / ((float)CC * (float)CC));

        float desc[3];
        desc[0] = tanhf(logf(fmaxf(batch_var,   EPSF)));
        desc[1] = tanhf(logf(fmaxf(sample_var,  EPSF)));
        desc[2] = tanhf(logf(fmaxf(channel_var, EPSF)));

        float lg[3];
        #pragma unroll
        for (int i = 0; i < 3; ++i) {
            lg[i] = gate_logits[i] + diag_proj[i*3+0]*desc[0]
                                   + diag_proj[i*3+1]*desc[1]
                                   + diag_proj[i*3+2]*desc[2];
        }
        const float m = fmaxf(lg[0], fmaxf(lg[1], lg[2]));
        const float e0 = expf(lg[0]-m), e1 = expf(lg[1]-m), e2 = expf(lg[2]-m);
        const float inv = 1.f / (e0 + e1 + e2);
        sh_gate[0] = e0 * inv; sh_gate[1] = e1 * inv; sh_gate[2] = e2 * inv;
    }
    __syncthreads();

    const float g0 = sh_gate[0], g1 = sh_gate[1], g2 = sh_gate[2];
    for (int i = tid; i < NN * CC; i += 256) {
        const int n = i >> 8, ch = i & 255, g = ch >> 5;
        const float w = weight[ch], bi = bias[ch];
        const float rb = sh_rs_b[ch], rl = sh_rs_l[n], rg = sh_rs_g[n*8+g];
        const float mb = sh_mu_b[ch], ml = sh_mu_l[n], mg = sh_mu_g[n*8+g];
        const float scale = g0*rb + g1*rl + g2*rg;
        const float offs  = g0*mb*rb + g1*ml*rl + g2*mg*rg;
        A[i] = w * scale;
        B[i] = bi - w * offs;
    }
}

// ---- kernel 4: y = x*A[nc] + B[nc], one block per (n,c) plane ------------
__global__ __launch_bounds__(256) void apply_kernel(
    const float4* __restrict__ x4, const float* __restrict__ A,
    const float* __restrict__ B, float4* __restrict__ y4)
{
    const int nc = blockIdx.x;
    const float a = A[nc], b = B[nc];
    const float4* xp = x4 + (size_t)nc * HW4;
    float4* yp = y4 + (size_t)nc * HW4;
    for (int i = threadIdx.x; i < HW4; i += 256) {
        float4 v = xp[i];
        v.x = fmaf(v.x, a, b);
        v.y = fmaf(v.y, a, b);
        v.z = fmaf(v.z, a, b);
        v.w = fmaf(v.w, a, b);
        yp[i] = v;
    }
}

extern "C" void kernel_launch(void* const* d_in, const int* in_sizes, int n_in,
                              void* d_out, int out_size, void* d_ws, size_t ws_size,
                              hipStream_t stream) {
    const float* x           = (const float*)d_in[0];
    const float* weight      = (const float*)d_in[1];
    const float* bias        = (const float*)d_in[2];
    const float* gate_logits = (const float*)d_in[3];
    const float* diag_proj   = (const float*)d_in[4];
    float* out = (float*)d_out;

    // ws layout (floats):
    float* ws   = (float*)d_ws;
    float* S1p  = ws;                        // NSTAT*256 = 802816
    float* S2p  = ws + 802816;               // 802816
    float* S1   = ws + 1605632;              // 8192
    float* S2   = ws + 1613824;              // 8192
    float* A    = ws + 1622016;              // 8192
    float* B    = ws + 1630208;              // 8192
    float* pT2  = ws + 1638400;              // 3136

    stats_kernel<<<NSTAT, 256, 0, stream>>>((const float4*)x, S1p, S2p, pT2);
    fold_kernel<<<NN, 256, 0, stream>>>(S1p, S2p, S1, S2);
    finalize_kernel<<<1, 256, 0, stream>>>(S1, S2, pT2, weight, bias,
                                           gate_logits, diag_proj, A, B);
    apply_kernel<<<NN * CC, 256, 0, stream>>>((const float4*)x, A, B, (float4*)out);
}

// Round 10
// 66.132 us; speedup vs baseline: 1.1806x; 1.0503x over previous
//
#include <hip/hip_runtime.h>
#include <hip/hip_bf16.h>

// Problem constants (N,C,H,W) = (32,256,56,56), GROUPS=8
#define NN 32
#define CC 256
#define HW 3136            // H*W
#define HW4 784            // float4 per (n,c) plane
#define CHW 802816
#define CHW4 200704        // float4 per sample
#define NCHW 25690112
#define GROUPS 8
#define CPG 32             // C/GROUPS
#define NHW 100352         // N*H*W (per-channel count)
#define GHW 100352         // CPG*HW (per-group count)
#define EPSF 1e-5f

#define PB16 49            // 16-f4 position blocks per sample (49*16 = 784)
#define NSTAT (NN*PB16)    // 1568 stats blocks
#define NPT2 NSTAT         // 1568 T^2 partials

typedef float f32x4 __attribute__((ext_vector_type(4)));

// ---- kernel 1: ONE read of x -> per-(n,c,pb) channel partials + T^2 ------
// block = (n, pb of 16 f4-positions, two octets); lane = (c_local 0..7, p 0..7);
// iter k: wave covers channels (k*4+w)*8 + c_local at the block's 16 positions.
__global__ __launch_bounds__(256) void stats_kernel(
    const float4* __restrict__ x4,
    float* __restrict__ S1p, float* __restrict__ S2p,   // [NSTAT][256]
    float* __restrict__ pT2)                            // [NSTAT]
{
    const int bx = blockIdx.x;
    const int n = bx / PB16, pb = bx - n * PB16;
    const int tid = threadIdx.x;
    const int w = tid >> 6, lane = tid & 63;
    const int cl = lane >> 3;          // channel-local 0..7
    const int pl = lane & 7;           // position-local 0..7
    const int P0 = pb * 16;

    const float4* base = x4 + (size_t)n * CHW4 + P0 + pl;

    float s1a[8], s2a[8];
    float4 T0 = make_float4(0.f, 0.f, 0.f, 0.f);
    float4 T1 = make_float4(0.f, 0.f, 0.f, 0.f);
    #pragma unroll
    for (int k = 0; k < 8; ++k) {
        const int c = (k * 4 + w) * 8 + cl;
        float4 v0 = base[(size_t)c * HW4];
        float4 v1 = base[(size_t)c * HW4 + 8];
        T0.x += v0.x; T0.y += v0.y; T0.z += v0.z; T0.w += v0.w;
        T1.x += v1.x; T1.y += v1.y; T1.z += v1.z; T1.w += v1.w;
        s1a[k] = v0.x + v0.y + v0.z + v0.w + v1.x + v1.y + v1.z + v1.w;
        s2a[k] = v0.x*v0.x + v0.y*v0.y + v0.z*v0.z + v0.w*v0.w
               + v1.x*v1.x + v1.y*v1.y + v1.z*v1.z + v1.w*v1.w;
    }

    // per-channel partials: reduce over the 8 p-lanes (consecutive lanes)
    #pragma unroll
    for (int k = 0; k < 8; ++k) {
        #pragma unroll
        for (int off = 1; off < 8; off <<= 1) {
            s1a[k] += __shfl_down(s1a[k], off, 64);
            s2a[k] += __shfl_down(s2a[k], off, 64);
        }
    }
    if (pl == 0) {
        #pragma unroll
        for (int k = 0; k < 8; ++k) {
            const int c = (k * 4 + w) * 8 + cl;
            S1p[(size_t)bx * 256 + c] = s1a[k];
            S2p[(size_t)bx * 256 + c] = s2a[k];
        }
    }

    // cross-channel T: reduce over the 8 c_local lanes (stride 8)
    #pragma unroll
    for (int off = 8; off < 64; off <<= 1) {
        T0.x += __shfl_xor(T0.x, off, 64);
        T0.y += __shfl_xor(T0.y, off, 64);
        T0.z += __shfl_xor(T0.z, off, 64);
        T0.w += __shfl_xor(T0.w, off, 64);
        T1.x += __shfl_xor(T1.x, off, 64);
        T1.y += __shfl_xor(T1.y, off, 64);
        T1.z += __shfl_xor(T1.z, off, 64);
        T1.w += __shfl_xor(T1.w, off, 64);
    }
    __shared__ float4 shT[4][16];
    if (lane < 8) {                    // cl==0 lanes hold the reduced sums
        shT[w][pl] = T0;
        shT[w][8 + pl] = T1;
    }
    __syncthreads();
    if (tid < 16) {
        float4 a = shT[0][tid], b = shT[1][tid], c4 = shT[2][tid], d = shT[3][tid];
        const float tx = a.x + b.x + c4.x + d.x;
        const float ty = a.y + b.y + c4.y + d.y;
        const float tz = a.z + b.z + c4.z + d.z;
        const float tw = a.w + b.w + c4.w + d.w;
        float t2 = tx*tx + ty*ty + tz*tz + tw*tw;
        #pragma unroll
        for (int off = 1; off < 16; off <<= 1) t2 += __shfl_down(t2, off, 64);
        if (tid == 0) pT2[bx] = t2;
    }
}

// ---- kernel 2: fold 49 position-partials -> S1/S2[n*256+c] ---------------
__global__ __launch_bounds__(256) void fold_kernel(
    const float* __restrict__ S1p, const float* __restrict__ S2p,
    float* __restrict__ S1, float* __restrict__ S2)
{
    const int n = blockIdx.x, c = threadIdx.x;
    const float* p1 = S1p + (size_t)n * PB16 * 256 + c;
    const float* p2 = S2p + (size_t)n * PB16 * 256 + c;
    float a = 0.f, b = 0.f;
    #pragma unroll 7
    for (int pb = 0; pb < PB16; ++pb) {
        a += p1[(size_t)pb * 256];
        b += p2[(size_t)pb * 256];
    }
    S1[n * 256 + c] = a;
    S2[n * 256 + c] = b;
}

// ---- kernel 3: all stats -> gates -> per-(n,c) affine coeffs A,B ---------
__global__ __launch_bounds__(256) void finalize_kernel(
    const float* __restrict__ S1, const float* __restrict__ S2,
    const float* __restrict__ partialT2,
    const float* __restrict__ weight, const float* __restrict__ bias,
    const float* __restrict__ gate_logits, const float* __restrict__ diag_proj,
    float* __restrict__ A, float* __restrict__ B)
{
    const int tid = threadIdx.x;
    __shared__ float sh_mu_b[CC], sh_rs_b[CC];
    __shared__ float sh_mu_g[NN * GROUPS], sh_rs_g[NN * GROUPS];
    __shared__ float sh_mu_l[NN], sh_rs_l[NN];
    __shared__ float sh_red1[4], sh_red2[4], sh_red3[4], sh_red4[4];
    __shared__ float sh_gate[3];

    const float inv_NHW  = 1.f / (float)NHW;
    const float inv_CHW  = 1.f / (float)CHW;
    const float inv_GHW  = 1.f / (float)GHW;
    const float inv_NCHW = 1.f / (float)NCHW;

    // BN: thread = channel
    const int c = tid;
    float s1 = 0.f, s2 = 0.f;
    for (int n = 0; n < NN; ++n) { s1 += S1[n * CC + c]; s2 += S2[n * CC + c]; }
    const float mu_b  = s1 * inv_NHW;
    const float var_b = s2 * inv_NHW - mu_b * mu_b;
    sh_mu_b[c] = mu_b;
    sh_rs_b[c] = rsqrtf(var_b + EPSF);

    // GN: thread = n*8+g
    const int ng_n = tid >> 3, ng_g = tid & 7;
    float s1g = 0.f, s2g = 0.f;
    for (int cc2 = 0; cc2 < CPG; ++cc2) {
        const int idx = ng_n * CC + ng_g * CPG + cc2;
        s1g += S1[idx]; s2g += S2[idx];
    }
    const float mu_g  = s1g * inv_GHW;
    const float var_g = s2g * inv_GHW - mu_g * mu_g;
    sh_mu_g[tid] = mu_g;
    sh_rs_g[tid] = rsqrtf(var_g + EPSF);

    // LN: reduce GN sums over the 8 groups of each sample
    float s1l = s1g, s2l = s2g;
    #pragma unroll
    for (int off = 1; off < 8; off <<= 1) {
        s1l += __shfl_xor(s1l, off, 64);
        s2l += __shfl_xor(s2l, off, 64);
    }
    float var_l_contrib = 0.f;
    if (ng_g == 0) {
        const float mu_l  = s1l * inv_CHW;
        const float var_l = s2l * inv_CHW - mu_l * mu_l;
        sh_mu_l[ng_n] = mu_l;
        sh_rs_l[ng_n] = rsqrtf(var_l + EPSF);
        var_l_contrib = var_l;
    }

    // T^2 partials
    float t2p = 0.f;
    for (int i = tid; i < NPT2; i += 256) t2p += partialT2[i];

    float r1 = var_b, r2 = s2, r3 = var_l_contrib, r4 = t2p;
    #pragma unroll
    for (int off = 32; off; off >>= 1) {
        r1 += __shfl_down(r1, off, 64);
        r2 += __shfl_down(r2, off, 64);
        r3 += __shfl_down(r3, off, 64);
        r4 += __shfl_down(r4, off, 64);
    }
    const int wave = tid >> 6, lane = tid & 63;
    if (lane == 0) { sh_red1[wave] = r1; sh_red2[wave] = r2; sh_red3[wave] = r3; sh_red4[wave] = r4; }
    __syncthreads();
    if (tid == 0) {
        const float sum_var_b = sh_red1[0] + sh_red1[1] + sh_red1[2] + sh_red1[3];
        const float total_x2  = sh_red2[0] + sh_red2[1] + sh_red2[2] + sh_red2[3];
        const float sum_var_l = sh_red3[0] + sh_red3[1] + sh_red3[2] + sh_red3[3];
        const float sum_T2    = sh_red4[0] + sh_red4[1] + sh_red4[2] + sh_red4[3];

        const float batch_var   = sum_var_b * (1.f / (float)CC);
        const float sample_var  = sum_var_l * (1.f / (float)NN);
        const float channel_var = total_x2 * inv_NCHW
                                - sum_T2 * inv_NHW * (1.f / ((float)CC * (float)CC));

        float desc[3];
        desc[0] = tanhf(logf(fmaxf(batch_var,   EPSF)));
        desc[1] = tanhf(logf(fmaxf(sample_var,  EPSF)));
        desc[2] = tanhf(logf(fmaxf(channel_var, EPSF)));

        float lg[3];
        #pragma unroll
        for (int i = 0; i < 3; ++i) {
            lg[i] = gate_logits[i] + diag_proj[i*3+0]*desc[0]
                                   + diag_proj[i*3+1]*desc[1]
                                   + diag_proj[i*3+2]*desc[2];
        }
        const float m = fmaxf(lg[0], fmaxf(lg[1], lg[2]));
        const float e0 = expf(lg[0]-m), e1 = expf(lg[1]-m), e2 = expf(lg[2]-m);
        const float inv = 1.f / (e0 + e1 + e2);
        sh_gate[0] = e0 * inv; sh_gate[1] = e1 * inv; sh_gate[2] = e2 * inv;
    }
    __syncthreads();

    const float g0 = sh_gate[0], g1 = sh_gate[1], g2 = sh_gate[2];
    for (int i = tid; i < NN * CC; i += 256) {
        const int n = i >> 8, ch = i & 255, g = ch >> 5;
        const float w = weight[ch], bi = bias[ch];
        const float rb = sh_rs_b[ch], rl = sh_rs_l[n], rg = sh_rs_g[n*8+g];
        const float mb = sh_mu_b[ch], ml = sh_mu_l[n], mg = sh_mu_g[n*8+g];
        const float scale = g0*rb + g1*rl + g2*rg;
        const float offs  = g0*mb*rb + g1*ml*rl + g2*mg*rg;
        A[i] = w * scale;
        B[i] = bi - w * offs;
    }
}

// ---- kernel 4: y = x*A[nc] + B[nc]; non-temporal y stores ----------------
// (y is write-once-read-never: nt keeps it from evicting x in L3, so the
//  next replay's stats pass re-reads x from L3 instead of HBM)
__global__ __launch_bounds__(256) void apply_kernel(
    const f32x4* __restrict__ x4, const float* __restrict__ A,
    const float* __restrict__ B, f32x4* __restrict__ y4)
{
    const int nc = blockIdx.x;
    const float a = A[nc], b = B[nc];
    const f32x4* xp = x4 + (size_t)nc * HW4;
    f32x4* yp = y4 + (size_t)nc * HW4;
    for (int i = threadIdx.x; i < HW4; i += 256) {
        f32x4 v = xp[i];
        f32x4 r;
        r.x = fmaf(v.x, a, b);
        r.y = fmaf(v.y, a, b);
        r.z = fmaf(v.z, a, b);
        r.w = fmaf(v.w, a, b);
        __builtin_nontemporal_store(r, &yp[i]);
    }
}

extern "C" void kernel_launch(void* const* d_in, const int* in_sizes, int n_in,
                              void* d_out, int out_size, void* d_ws, size_t ws_size,
                              hipStream_t stream) {
    const float* x           = (const float*)d_in[0];
    const float* weight      = (const float*)d_in[1];
    const float* bias        = (const float*)d_in[2];
    const float* gate_logits = (const float*)d_in[3];
    const float* diag_proj   = (const float*)d_in[4];
    float* out = (float*)d_out;

    // ws layout (floats):
    float* ws   = (float*)d_ws;
    float* S1p  = ws;                        // NSTAT*256 = 401408
    float* S2p  = ws + 401408;               // 401408
    float* S1   = ws + 802816;               // 8192
    float* S2   = ws + 811008;               // 8192
    float* A    = ws + 819200;               // 8192
    float* B    = ws + 827392;               // 8192
    float* pT2  = ws + 835584;               // 1568

    stats_kernel<<<NSTAT, 256, 0, stream>>>((const float4*)x, S1p, S2p, pT2);
    fold_kernel<<<NN, 256, 0, stream>>>(S1p, S2p, S1, S2);
    finalize_kernel<<<1, 256, 0, stream>>>(S1, S2, pT2, weight, bias,
                                           gate_logits, diag_proj, A, B);
    apply_kernel<<<NN * CC, 256, 0, stream>>>((const f32x4*)x, A, B, (f32x4*)out);
}

// Round 11
// 62.821 us; speedup vs baseline: 1.2428x; 1.0527x over previous
//
#include <hip/hip_runtime.h>
#include <hip/hip_bf16.h>

// Problem constants (N,C,H,W) = (32,256,56,56), GROUPS=8
#define NN 32
#define CC 256
#define HW 3136            // H*W
#define HW4 784            // float4 per (n,c) plane
#define CHW 802816
#define CHW4 200704        // float4 per sample
#define NCHW 25690112
#define GROUPS 8
#define CPG 32             // C/GROUPS
#define NHW 100352         // N*H*W (per-channel count)
#define GHW 100352         // CPG*HW (per-group count)
#define EPSF 1e-5f

#define PB16 49            // 16-f4 position blocks per sample (49*16 = 784)
#define NSTAT (NN*PB16)    // 1568 stats blocks
#define NPT2 NSTAT         // 1568 T^2 partials

typedef float f32x4 __attribute__((ext_vector_type(4)));

// ---- kernel 1: ONE read of x -> per-(n,c,pb) {S1,S2} float2 partials + T^2
// block = (n, pb of 16 f4-positions); lane = (c_local 0..7, p 0..7);
// iter k: wave covers channels (k*4+w)*8 + c_local at the block's 16 positions.
__global__ __launch_bounds__(256) void stats_kernel(
    const float4* __restrict__ x4,
    float2* __restrict__ S12p,          // [NSTAT][256] {s1,s2}
    float* __restrict__ pT2)            // [NSTAT]
{
    const int bx = blockIdx.x;
    const int n = bx / PB16, pb = bx - n * PB16;
    const int tid = threadIdx.x;
    const int w = tid >> 6, lane = tid & 63;
    const int cl = lane >> 3;          // channel-local 0..7
    const int pl = lane & 7;           // position-local 0..7
    const int P0 = pb * 16;

    const float4* base = x4 + (size_t)n * CHW4 + P0 + pl;

    float s1a[8], s2a[8];
    float4 T0 = make_float4(0.f, 0.f, 0.f, 0.f);
    float4 T1 = make_float4(0.f, 0.f, 0.f, 0.f);
    #pragma unroll
    for (int k = 0; k < 8; ++k) {
        const int c = (k * 4 + w) * 8 + cl;
        float4 v0 = base[(size_t)c * HW4];
        float4 v1 = base[(size_t)c * HW4 + 8];
        T0.x += v0.x; T0.y += v0.y; T0.z += v0.z; T0.w += v0.w;
        T1.x += v1.x; T1.y += v1.y; T1.z += v1.z; T1.w += v1.w;
        s1a[k] = v0.x + v0.y + v0.z + v0.w + v1.x + v1.y + v1.z + v1.w;
        s2a[k] = v0.x*v0.x + v0.y*v0.y + v0.z*v0.z + v0.w*v0.w
               + v1.x*v1.x + v1.y*v1.y + v1.z*v1.z + v1.w*v1.w;
    }

    // per-channel partials: reduce over the 8 p-lanes (consecutive lanes)
    #pragma unroll
    for (int k = 0; k < 8; ++k) {
        #pragma unroll
        for (int off = 1; off < 8; off <<= 1) {
            s1a[k] += __shfl_down(s1a[k], off, 64);
            s2a[k] += __shfl_down(s2a[k], off, 64);
        }
    }
    if (pl == 0) {
        #pragma unroll
        for (int k = 0; k < 8; ++k) {
            const int c = (k * 4 + w) * 8 + cl;
            S12p[(size_t)bx * 256 + c] = make_float2(s1a[k], s2a[k]);
        }
    }

    // cross-channel T: reduce over the 8 c_local lanes (stride 8)
    #pragma unroll
    for (int off = 8; off < 64; off <<= 1) {
        T0.x += __shfl_xor(T0.x, off, 64);
        T0.y += __shfl_xor(T0.y, off, 64);
        T0.z += __shfl_xor(T0.z, off, 64);
        T0.w += __shfl_xor(T0.w, off, 64);
        T1.x += __shfl_xor(T1.x, off, 64);
        T1.y += __shfl_xor(T1.y, off, 64);
        T1.z += __shfl_xor(T1.z, off, 64);
        T1.w += __shfl_xor(T1.w, off, 64);
    }
    __shared__ float4 shT[4][16];
    if (lane < 8) {                    // cl==0 lanes hold the reduced sums
        shT[w][pl] = T0;
        shT[w][8 + pl] = T1;
    }
    __syncthreads();
    if (tid < 16) {
        float4 a = shT[0][tid], b = shT[1][tid], c4 = shT[2][tid], d = shT[3][tid];
        const float tx = a.x + b.x + c4.x + d.x;
        const float ty = a.y + b.y + c4.y + d.y;
        const float tz = a.z + b.z + c4.z + d.z;
        const float tw = a.w + b.w + c4.w + d.w;
        float t2 = tx*tx + ty*ty + tz*tz + tw*tw;
        #pragma unroll
        for (int off = 1; off < 16; off <<= 1) t2 += __shfl_down(t2, off, 64);
        if (tid == 0) pT2[bx] = t2;
    }
}

// ---- kernel 2: fold 49 position-partials -> S12[n*256+c] -----------------
__global__ __launch_bounds__(256) void fold_kernel(
    const float2* __restrict__ S12p, float2* __restrict__ S12)
{
    const int n = blockIdx.x, c = threadIdx.x;
    const float2* p = S12p + (size_t)n * PB16 * 256 + c;
    float a = 0.f, b = 0.f;
    #pragma unroll 7
    for (int pb = 0; pb < PB16; ++pb) {
        float2 v = p[(size_t)pb * 256];
        a += v.x; b += v.y;
    }
    S12[n * 256 + c] = make_float2(a, b);
}

// ---- kernel 3: stats -> gates + compact norm coefficients ----------------
//  CB[c]  = {mu_b, rs_b}   per channel
//  CL[n]  = {mu_l, rs_l}   per sample
//  CG[ng] = {mu_g, rs_g}   per (n,group)
//  GT[0..2] = softmax gates
__global__ __launch_bounds__(256) void finalize_kernel(
    const float2* __restrict__ S12, const float* __restrict__ partialT2,
    const float* __restrict__ gate_logits, const float* __restrict__ diag_proj,
    float2* __restrict__ CB, float2* __restrict__ CL, float2* __restrict__ CG,
    float* __restrict__ GT)
{
    const int tid = threadIdx.x;
    __shared__ float sh_red1[4], sh_red2[4], sh_red3[4], sh_red4[4];

    const float inv_NHW  = 1.f / (float)NHW;
    const float inv_CHW  = 1.f / (float)CHW;
    const float inv_GHW  = 1.f / (float)GHW;
    const float inv_NCHW = 1.f / (float)NCHW;

    // BN: thread = channel
    const int c = tid;
    float s1 = 0.f, s2 = 0.f;
    for (int n = 0; n < NN; ++n) {
        float2 v = S12[n * CC + c];
        s1 += v.x; s2 += v.y;
    }
    const float mu_b  = s1 * inv_NHW;
    const float var_b = s2 * inv_NHW - mu_b * mu_b;
    CB[c] = make_float2(mu_b, rsqrtf(var_b + EPSF));

    // GN: thread = n*8+g
    const int ng_n = tid >> 3, ng_g = tid & 7;
    float s1g = 0.f, s2g = 0.f;
    for (int cc2 = 0; cc2 < CPG; ++cc2) {
        float2 v = S12[ng_n * CC + ng_g * CPG + cc2];
        s1g += v.x; s2g += v.y;
    }
    const float mu_g  = s1g * inv_GHW;
    const float var_g = s2g * inv_GHW - mu_g * mu_g;
    CG[tid] = make_float2(mu_g, rsqrtf(var_g + EPSF));

    // LN: reduce GN sums over the 8 groups of each sample
    float s1l = s1g, s2l = s2g;
    #pragma unroll
    for (int off = 1; off < 8; off <<= 1) {
        s1l += __shfl_xor(s1l, off, 64);
        s2l += __shfl_xor(s2l, off, 64);
    }
    float var_l_contrib = 0.f;
    if (ng_g == 0) {
        const float mu_l  = s1l * inv_CHW;
        const float var_l = s2l * inv_CHW - mu_l * mu_l;
        CL[ng_n] = make_float2(mu_l, rsqrtf(var_l + EPSF));
        var_l_contrib = var_l;
    }

    // T^2 partials
    float t2p = 0.f;
    for (int i = tid; i < NPT2; i += 256) t2p += partialT2[i];

    float r1 = var_b, r2 = s2, r3 = var_l_contrib, r4 = t2p;
    #pragma unroll
    for (int off = 32; off; off >>= 1) {
        r1 += __shfl_down(r1, off, 64);
        r2 += __shfl_down(r2, off, 64);
        r3 += __shfl_down(r3, off, 64);
        r4 += __shfl_down(r4, off, 64);
    }
    const int wave = tid >> 6, lane = tid & 63;
    if (lane == 0) { sh_red1[wave] = r1; sh_red2[wave] = r2; sh_red3[wave] = r3; sh_red4[wave] = r4; }
    __syncthreads();
    if (tid == 0) {
        const float sum_var_b = sh_red1[0] + sh_red1[1] + sh_red1[2] + sh_red1[3];
        const float total_x2  = sh_red2[0] + sh_red2[1] + sh_red2[2] + sh_red2[3];
        const float sum_var_l = sh_red3[0] + sh_red3[1] + sh_red3[2] + sh_red3[3];
        const float sum_T2    = sh_red4[0] + sh_red4[1] + sh_red4[2] + sh_red4[3];

        const float batch_var   = sum_var_b * (1.f / (float)CC);
        const float sample_var  = sum_var_l * (1.f / (float)NN);
        const float channel_var = total_x2 * inv_NCHW
                                - sum_T2 * inv_NHW * (1.f / ((float)CC * (float)CC));

        float desc[3];
        desc[0] = tanhf(logf(fmaxf(batch_var,   EPSF)));
        desc[1] = tanhf(logf(fmaxf(sample_var,  EPSF)));
        desc[2] = tanhf(logf(fmaxf(channel_var, EPSF)));

        float lg[3];
        #pragma unroll
        for (int i = 0; i < 3; ++i) {
            lg[i] = gate_logits[i] + diag_proj[i*3+0]*desc[0]
                                   + diag_proj[i*3+1]*desc[1]
                                   + diag_proj[i*3+2]*desc[2];
        }
        const float m = fmaxf(lg[0], fmaxf(lg[1], lg[2]));
        const float e0 = expf(lg[0]-m), e1 = expf(lg[1]-m), e2 = expf(lg[2]-m);
        const float inv = 1.f / (e0 + e1 + e2);
        GT[0] = e0 * inv; GT[1] = e1 * inv; GT[2] = e2 * inv;
    }
}

// ---- kernel 4: y = x*a + b; a,b computed per block; nt stores ------------
__global__ __launch_bounds__(256) void apply_kernel(
    const f32x4* __restrict__ x4,
    const float* __restrict__ weight, const float* __restrict__ bias,
    const float2* __restrict__ CB, const float2* __restrict__ CL,
    const float2* __restrict__ CG, const float* __restrict__ GT,
    f32x4* __restrict__ y4)
{
    const int nc = blockIdx.x;
    const int n = nc >> 8, ch = nc & 255, g = ch >> 5;
    const float g0 = GT[0], g1 = GT[1], g2 = GT[2];
    const float2 cb = CB[ch], cl2 = CL[n], cg2 = CG[n * 8 + g];
    const float w = weight[ch], bi = bias[ch];
    const float scale = g0 * cb.y + g1 * cl2.y + g2 * cg2.y;
    const float offs  = g0 * cb.x * cb.y + g1 * cl2.x * cl2.y + g2 * cg2.x * cg2.y;
    const float a = w * scale;
    const float b = fmaf(-w, offs, bi);

    const f32x4* xp = x4 + (size_t)nc * HW4;
    f32x4* yp = y4 + (size_t)nc * HW4;
    const int tid = threadIdx.x;

    // batch the independent loads (3 full strides + 16-wide tail), then store
    f32x4 v0 = xp[tid];
    f32x4 v1 = xp[tid + 256];
    f32x4 v2 = xp[tid + 512];
    f32x4 v3;
    if (tid < 16) v3 = xp[tid + 768];

    f32x4 r0, r1, r2, r3;
    r0.x = fmaf(v0.x, a, b); r0.y = fmaf(v0.y, a, b); r0.z = fmaf(v0.z, a, b); r0.w = fmaf(v0.w, a, b);
    r1.x = fmaf(v1.x, a, b); r1.y = fmaf(v1.y, a, b); r1.z = fmaf(v1.z, a, b); r1.w = fmaf(v1.w, a, b);
    r2.x = fmaf(v2.x, a, b); r2.y = fmaf(v2.y, a, b); r2.z = fmaf(v2.z, a, b); r2.w = fmaf(v2.w, a, b);
    __builtin_nontemporal_store(r0, &yp[tid]);
    __builtin_nontemporal_store(r1, &yp[tid + 256]);
    __builtin_nontemporal_store(r2, &yp[tid + 512]);
    if (tid < 16) {
        r3.x = fmaf(v3.x, a, b); r3.y = fmaf(v3.y, a, b); r3.z = fmaf(v3.z, a, b); r3.w = fmaf(v3.w, a, b);
        __builtin_nontemporal_store(r3, &yp[tid + 768]);
    }
}

extern "C" void kernel_launch(void* const* d_in, const int* in_sizes, int n_in,
                              void* d_out, int out_size, void* d_ws, size_t ws_size,
                              hipStream_t stream) {
    const float* x           = (const float*)d_in[0];
    const float* weight      = (const float*)d_in[1];
    const float* bias        = (const float*)d_in[2];
    const float* gate_logits = (const float*)d_in[3];
    const float* diag_proj   = (const float*)d_in[4];
    float* out = (float*)d_out;

    // ws layout (float offsets; all float2 users even-aligned)
    float* ws   = (float*)d_ws;
    float2* S12p = (float2*)ws;                  // NSTAT*256 float2 = 802816 f
    float2* S12  = (float2*)(ws + 802816);       // 8192 float2 = 16384 f
    float2* CB   = (float2*)(ws + 819200);       // 256 float2
    float2* CL   = (float2*)(ws + 819712);       // 32 float2
    float2* CG   = (float2*)(ws + 819776);       // 256 float2
    float*  GT   = ws + 820288;                  // 4
    float*  pT2  = ws + 820296;                  // 1568

    stats_kernel<<<NSTAT, 256, 0, stream>>>((const float4*)x, S12p, pT2);
    fold_kernel<<<NN, 256, 0, stream>>>(S12p, S12);
    finalize_kernel<<<1, 256, 0, stream>>>(S12, pT2, gate_logits, diag_proj,
                                           CB, CL, CG, GT);
    apply_kernel<<<NN * CC, 256, 0, stream>>>((const f32x4*)x, weight, bias,
                                              CB, CL, CG, GT, (f32x4*)out);
}